// Round 3
// baseline (121.015 us; speedup 1.0000x reference)
//
#include <hip/hip_runtime.h>

// Problem constants (match reference)
#define BB 64
#define PP 8400
#define TT 100
#define TG 10            // targets per block; TT % TG == 0
#define NGRP (TT / TG)   // 10 groups per batch

// Kernel 1: one block per (b, target-group). Threads stride P; each loaded
// prediction is scored against TG targets (corner math + loads amortized).
// Block writes sum of its TG masked squared errors to ws[blockIdx.x].
__global__ __launch_bounds__(256) void yolo_match_kernel(
    const float* __restrict__ pred,    // [B, P, 5]
    const float* __restrict__ tgt,     // [B, T, 5]
    const int*   __restrict__ lengths, // [B]
    float* __restrict__ ws)            // [B*NGRP] block partial sums
{
#pragma clang fp contract(off)
    const int blk = blockIdx.x;
    const int b   = blk / NGRP;
    const int grp = blk - b * NGRP;
    const int t0  = grp * TG;
    const int tid = threadIdx.x;

    const float* pb = pred + (size_t)b * PP * 5;
    const float* tb = tgt  + ((size_t)b * TT + t0) * 5;

    // Per-target corners + area, kept in registers (fully unrolled).
    float tx1[TG], ty1[TG], tx2[TG], ty2[TG], ta[TG];
#pragma unroll
    for (int g = 0; g < TG; ++g) {
        const float tcx = tb[g * 5 + 1], tcy = tb[g * 5 + 2];
        const float tw  = tb[g * 5 + 3], th  = tb[g * 5 + 4];
        tx1[g] = tcx - tw * 0.5f;
        ty1[g] = tcy - th * 0.5f;
        tx2[g] = tcx + tw * 0.5f;
        ty2[g] = tcy + th * 0.5f;
        ta[g]  = (tx2[g] - tx1[g]) * (ty2[g] - ty1[g]);
    }

    float best[TG];
    int   bidx[TG];
#pragma unroll
    for (int g = 0; g < TG; ++g) { best[g] = -1.0f; bidx[g] = 0; }

    for (int p = tid; p < PP; p += 256) {
        const float* bp = pb + p * 5;
        const float cx = bp[1], cy = bp[2], w = bp[3], h = bp[4];
        const float px1 = cx - w * 0.5f;
        const float py1 = cy - h * 0.5f;
        const float px2 = cx + w * 0.5f;
        const float py2 = cy + h * 0.5f;
        const float area_p = (px2 - px1) * (py2 - py1);

#pragma unroll
        for (int g = 0; g < TG; ++g) {
            const float ix1 = fmaxf(px1, tx1[g]);
            const float iy1 = fmaxf(py1, ty1[g]);
            const float ix2 = fminf(px2, tx2[g]);
            const float iy2 = fminf(py2, ty2[g]);
            const float inter = fmaxf(ix2 - ix1, 0.0f) * fmaxf(iy2 - iy1, 0.0f);
            // numpy eval order: ((area_p + area_t) - inter) + 1e-6
            const float denom = ((area_p + ta[g]) - inter) + 1e-6f;
            const float iou   = inter / denom;   // IEEE div — must match numpy bits
            if (iou > best[g]) { best[g] = iou; bidx[g] = p; }
        }
    }

    // Reduce: wave-level shuffle, then cross-wave via LDS.
    const int lane = tid & 63;
    const int wid  = tid >> 6;  // 0..3
    __shared__ float s_best[4][TG];
    __shared__ int   s_bidx[4][TG];
    __shared__ float s_sq[TG];

#pragma unroll
    for (int g = 0; g < TG; ++g) {
        float bv = best[g];
        int   bi = bidx[g];
        for (int off = 32; off > 0; off >>= 1) {
            const float ob = __shfl_down(bv, off, 64);
            const int   oi = __shfl_down(bi, off, 64);
            if (ob > bv || (ob == bv && oi < bi)) { bv = ob; bi = oi; }
        }
        if (lane == 0) { s_best[wid][g] = bv; s_bidx[wid][g] = bi; }
    }
    __syncthreads();

    if (tid < TG) {
        const int g = tid;
        float bv = s_best[0][g];
        int   bi = s_bidx[0][g];
#pragma unroll
        for (int w = 1; w < 4; ++w) {
            const float ob = s_best[w][g];
            const int   oi = s_bidx[w][g];
            if (ob > bv || (ob == bv && oi < bi)) { bv = ob; bi = oi; }
        }
        const float* mp = pb + bi * 5;
        const float* tp = tb + g * 5;
        float sq = 0.0f;
        for (int k = 0; k < 5; ++k) {
            const float d = mp[k] - tp[k];
            sq += d * d;
        }
        const bool valid = ((t0 + g) < lengths[b]);
        s_sq[g] = valid ? sq : 0.0f;
    }
    __syncthreads();

    if (tid == 0) {
        float s = 0.0f;
#pragma unroll
        for (int g = 0; g < TG; ++g) s += s_sq[g];
        ws[blk] = s;
    }
}

// Kernel 2: sum ws[0 .. B*NGRP) -> out[0] = sum / B   (deterministic order)
__global__ __launch_bounds__(256) void yolo_reduce_kernel(
    const float* __restrict__ ws,
    float* __restrict__ out)
{
    const int tid = threadIdx.x;
    float s = 0.0f;
    for (int i = tid; i < BB * NGRP; i += 256) s += ws[i];

    __shared__ float sm[256];
    sm[tid] = s;
    __syncthreads();
    for (int off = 128; off > 0; off >>= 1) {
        if (tid < off) sm[tid] += sm[tid + off];
        __syncthreads();
    }
    if (tid == 0) out[0] = sm[0] / (float)BB;
}

extern "C" void kernel_launch(void* const* d_in, const int* in_sizes, int n_in,
                              void* d_out, int out_size, void* d_ws, size_t ws_size,
                              hipStream_t stream) {
    const float* pred    = (const float*)d_in[0]; // [B,P,5] f32
    const float* tgt     = (const float*)d_in[1]; // [B,T,5] f32
    const int*   lengths = (const int*)d_in[2];   // [B]
    float* out = (float*)d_out;
    float* ws  = (float*)d_ws;                    // B*NGRP floats = 2.56 KB

    yolo_match_kernel<<<BB * NGRP, 256, 0, stream>>>(pred, tgt, lengths, ws);
    yolo_reduce_kernel<<<1, 256, 0, stream>>>(ws, out);
}

// Round 4
// 103.488 us; speedup vs baseline: 1.1694x; 1.1694x over previous
//
#include <hip/hip_runtime.h>

// Problem constants (match reference)
#define BB 64
#define PP 8400
#define TT 100
#define TG 5             // targets per block
#define NGRP (TT / TG)   // 20 groups per batch -> grid = 64*20 = 1280 = 5 blocks/CU

// Kernel 1: one block per (batch, target-group-of-5). Threads process 4
// consecutive pred boxes at a time (5x float4 coalesced loads), scoring each
// against the 5 targets. Block-level XCD swizzle keeps all 20 blocks of a
// batch on one XCD so the 168 KB pred panel stays L2-resident.
__global__ __launch_bounds__(256) void yolo_match_kernel(
    const float* __restrict__ pred,    // [B, P, 5]
    const float* __restrict__ tgt,     // [B, T, 5]
    const int*   __restrict__ lengths, // [B]
    float* __restrict__ ws)            // [B*NGRP] block partial sums
{
#pragma clang fp contract(off)
    // XCD-aware decode: hardware assigns block i -> XCD (i % 8).
    // blk = x + 8*(bhi*NGRP + grp), b = x + 8*bhi  => all grps of b share XCD x.
    const int blkraw = blockIdx.x;
    const int x    = blkraw & 7;
    const int r    = blkraw >> 3;          // 0..159
    const int bhi  = r / NGRP;             // 0..7
    const int grp  = r - bhi * NGRP;       // 0..19
    const int b    = x + 8 * bhi;          // 0..63
    const int t0   = grp * TG;
    const int tid  = threadIdx.x;

    const float*  pb  = pred + (size_t)b * PP * 5;
    const float4* pb4 = (const float4*)pb;           // batch panel is 16B-aligned
    const float*  tb  = tgt + ((size_t)b * TT + t0) * 5;

    // Per-target corners + area in registers.
    float tx1[TG], ty1[TG], tx2[TG], ty2[TG], ta[TG];
#pragma unroll
    for (int g = 0; g < TG; ++g) {
        const float tcx = tb[g * 5 + 1], tcy = tb[g * 5 + 2];
        const float tw  = tb[g * 5 + 3], th  = tb[g * 5 + 4];
        tx1[g] = tcx - tw * 0.5f;
        ty1[g] = tcy - th * 0.5f;
        tx2[g] = tcx + tw * 0.5f;
        ty2[g] = tcy + th * 0.5f;
        ta[g]  = (tx2[g] - tx1[g]) * (ty2[g] - ty1[g]);
    }

    float best[TG];
    int   bidx[TG];
#pragma unroll
    for (int g = 0; g < TG; ++g) { best[g] = -1.0f; bidx[g] = 0; }

    // 4 boxes per thread-iteration: 20 floats = 5 aligned float4 loads.
    for (int g0 = tid; g0 < PP / 4; g0 += 256) {
        const float4 v0 = pb4[g0 * 5 + 0];
        const float4 v1 = pb4[g0 * 5 + 1];
        const float4 v2 = pb4[g0 * 5 + 2];
        const float4 v3 = pb4[g0 * 5 + 3];
        const float4 v4 = pb4[g0 * 5 + 4];
        // box j fields (conf,cx,cy,w,h) at float offset 5j within the 20:
        const float cxs[4] = { v0.y, v1.z, v2.w, v4.x };
        const float cys[4] = { v0.z, v1.w, v3.x, v4.y };
        const float wss[4] = { v0.w, v2.x, v3.y, v4.z };
        const float hss[4] = { v1.x, v2.y, v3.z, v4.w };

#pragma unroll
        for (int j = 0; j < 4; ++j) {
            const float px1 = cxs[j] - wss[j] * 0.5f;
            const float py1 = cys[j] - hss[j] * 0.5f;
            const float px2 = cxs[j] + wss[j] * 0.5f;
            const float py2 = cys[j] + hss[j] * 0.5f;
            const float area_p = (px2 - px1) * (py2 - py1);
            const int   p = g0 * 4 + j;

#pragma unroll
            for (int g = 0; g < TG; ++g) {
                const float ix1 = fmaxf(px1, tx1[g]);
                const float iy1 = fmaxf(py1, ty1[g]);
                const float ix2 = fminf(px2, tx2[g]);
                const float iy2 = fminf(py2, ty2[g]);
                const float inter = fmaxf(ix2 - ix1, 0.0f) * fmaxf(iy2 - iy1, 0.0f);
                // numpy eval order: ((area_p + area_t) - inter) + 1e-6
                const float denom = ((area_p + ta[g]) - inter) + 1e-6f;
                const float iou   = inter / denom;   // IEEE div — bit-match numpy
                if (iou > best[g]) { best[g] = iou; bidx[g] = p; }
            }
        }
    }

    // Reduce: wave-level shuffle, then cross-wave via LDS.
    const int lane = tid & 63;
    const int wid  = tid >> 6;  // 0..3
    __shared__ float s_best[4][TG];
    __shared__ int   s_bidx[4][TG];
    __shared__ float s_sq[TG];

#pragma unroll
    for (int g = 0; g < TG; ++g) {
        float bv = best[g];
        int   bi = bidx[g];
        for (int off = 32; off > 0; off >>= 1) {
            const float ob = __shfl_down(bv, off, 64);
            const int   oi = __shfl_down(bi, off, 64);
            if (ob > bv || (ob == bv && oi < bi)) { bv = ob; bi = oi; }
        }
        if (lane == 0) { s_best[wid][g] = bv; s_bidx[wid][g] = bi; }
    }
    __syncthreads();

    if (tid < TG) {
        const int g = tid;
        float bv = s_best[0][g];
        int   bi = s_bidx[0][g];
#pragma unroll
        for (int w = 1; w < 4; ++w) {
            const float ob = s_best[w][g];
            const int   oi = s_bidx[w][g];
            if (ob > bv || (ob == bv && oi < bi)) { bv = ob; bi = oi; }
        }
        const float* mp = pb + bi * 5;
        const float* tp = tb + g * 5;
        float sq = 0.0f;
        for (int k = 0; k < 5; ++k) {
            const float d = mp[k] - tp[k];
            sq += d * d;
        }
        const bool valid = ((t0 + g) < lengths[b]);
        s_sq[g] = valid ? sq : 0.0f;
    }
    __syncthreads();

    if (tid == 0) {
        float s = 0.0f;
#pragma unroll
        for (int g = 0; g < TG; ++g) s += s_sq[g];
        ws[blkraw] = s;
    }
}

// Kernel 2: sum ws[0 .. B*NGRP) -> out[0] = sum / B
__global__ __launch_bounds__(256) void yolo_reduce_kernel(
    const float* __restrict__ ws,
    float* __restrict__ out)
{
    const int tid = threadIdx.x;
    float s = 0.0f;
    for (int i = tid; i < BB * NGRP; i += 256) s += ws[i];

    __shared__ float sm[256];
    sm[tid] = s;
    __syncthreads();
    for (int off = 128; off > 0; off >>= 1) {
        if (tid < off) sm[tid] += sm[tid + off];
        __syncthreads();
    }
    if (tid == 0) out[0] = sm[0] / (float)BB;
}

extern "C" void kernel_launch(void* const* d_in, const int* in_sizes, int n_in,
                              void* d_out, int out_size, void* d_ws, size_t ws_size,
                              hipStream_t stream) {
    const float* pred    = (const float*)d_in[0]; // [B,P,5] f32
    const float* tgt     = (const float*)d_in[1]; // [B,T,5] f32
    const int*   lengths = (const int*)d_in[2];   // [B]
    float* out = (float*)d_out;
    float* ws  = (float*)d_ws;                    // B*NGRP floats = 5.12 KB

    yolo_match_kernel<<<BB * NGRP, 256, 0, stream>>>(pred, tgt, lengths, ws);
    yolo_reduce_kernel<<<1, 256, 0, stream>>>(ws, out);
}